// Round 5
// baseline (339.781 us; speedup 1.0000x reference)
//
#include <hip/hip_runtime.h>
#include <hip/hip_bf16.h>

// Problem constants
#define BATCH 2
#define LSEQ 2048
#define DMODEL 1024
#define NH 16
#define DQK 16
#define DV 64
#define FDIM 273            // 1 + 16 + 256
#define CHUNK 128
#define NCH (LSEQ / CHUNK)  // 16 chunks per batch row
#define ROWS (BATCH * LSEQ) // 4096
#define C2 0.17677669529663687f  // 1/(4*sqrt(2))

typedef short bf16x8 __attribute__((ext_vector_type(8)));
typedef float f32x4 __attribute__((ext_vector_type(4)));

__device__ __forceinline__ unsigned short f2bf(float f) {
  __hip_bfloat16 h = __float2bfloat16(f);
  unsigned short u; __builtin_memcpy(&u, &h, 2); return u;
}

// ---------------------------------------------------------------------------
// fp32 -> bf16 elementwise cast (float4 / ushort4 vectorized)
// ---------------------------------------------------------------------------
__global__ __launch_bounds__(256) void cast4(const float* __restrict__ in,
                                             unsigned short* __restrict__ out, int n4) {
  int i = blockIdx.x * 256 + threadIdx.x;
  if (i >= n4) return;
  float4 v = ((const float4*)in)[i];
  ushort4 o = {f2bf(v.x), f2bf(v.y), f2bf(v.z), f2bf(v.w)};
  ((ushort4*)out)[i] = o;
}

// ---------------------------------------------------------------------------
// W (KxN fp32, row-major) -> Wt (NxK bf16, row-major).  32x32 LDS tile.
// ---------------------------------------------------------------------------
__global__ __launch_bounds__(256) void transpose_cast(
    const float* __restrict__ W, unsigned short* __restrict__ Wt, int K, int N) {
  __shared__ float t[32][33];
  const int kb = blockIdx.y * 32, nb = blockIdx.x * 32;
  const int tx = threadIdx.x & 31, ty4 = (threadIdx.x >> 5) * 4;
#pragma unroll
  for (int r = 0; r < 4; r++)
    t[ty4 + r][tx] = W[(size_t)(kb + ty4 + r) * N + nb + tx];
  __syncthreads();
#pragma unroll
  for (int r = 0; r < 4; r++)
    Wt[(size_t)(nb + ty4 + r) * K + kb + tx] = f2bf(t[tx][ty4 + r]);
}

// ---------------------------------------------------------------------------
// MFMA GEMM (m97 pattern): C(MxN fp32) = A(MxK bf16) @ Bt(NxK bf16)^T.
// 128x128 tile, BK=32, 256 threads = 4 waves, each wave a 64x64 quadrant.
// ---------------------------------------------------------------------------
__global__ __launch_bounds__(256) void gemm_mfma(
    const unsigned short* __restrict__ A, const unsigned short* __restrict__ Bt,
    float* __restrict__ C, int M, int N, int K) {
  __shared__ unsigned short As[512 * 8];
  __shared__ unsigned short Bs[512 * 8];
  const int tid = threadIdx.x;
  const int bm = blockIdx.y * 128, bn = blockIdx.x * 128;
  const int lane = tid & 63;
  const int w = tid >> 6;
  const int qr = (w >> 1) * 64, qc = (w & 1) * 64;
  f32x4 acc[4][4] = {};

  for (int k0 = 0; k0 < K; k0 += 32) {
#pragma unroll
    for (int j = 0; j < 4; ++j) {
      int c = j * 256 + tid;
      int cc = c & 511;
      int row = ((cc >> 6) << 4) + (cc & 15);
      int kh = (cc >> 4) & 3;
      const unsigned short* gp;
      unsigned short* lp;
      if (c < 512) { gp = A  + (size_t)(bm + row) * K + k0 + kh * 8; lp = As + cc * 8; }
      else         { gp = Bt + (size_t)(bn + row) * K + k0 + kh * 8; lp = Bs + cc * 8; }
      __builtin_amdgcn_global_load_lds(
          (const __attribute__((address_space(1))) unsigned int*)(const void*)gp,
          (__attribute__((address_space(3))) unsigned int*)lp, 16, 0, 0);
    }
    __syncthreads();
    bf16x8 a[4], b[4];
#pragma unroll
    for (int i = 0; i < 4; ++i) {
      a[i] = *(const bf16x8*)(As + ((qr >> 4) + i) * 512 + lane * 8);
      b[i] = *(const bf16x8*)(Bs + ((qc >> 4) + i) * 512 + lane * 8);
    }
#pragma unroll
    for (int i = 0; i < 4; ++i)
#pragma unroll
      for (int jj = 0; jj < 4; ++jj)
        acc[i][jj] = __builtin_amdgcn_mfma_f32_16x16x32_bf16(a[i], b[jj], acc[i][jj], 0, 0, 0);
    __syncthreads();
  }
  const int cn = lane & 15, r0 = (lane >> 4) * 4;
#pragma unroll
  for (int i = 0; i < 4; ++i)
#pragma unroll
    for (int jj = 0; jj < 4; ++jj) {
      size_t base = (size_t)(bm + qr + i * 16 + r0) * N + bn + qc + jj * 16 + cn;
#pragma unroll
      for (int r = 0; r < 4; ++r) C[base + (size_t)r * N] = acc[i][jj][r];
    }
}

// ---------------------------------------------------------------------------
// Pass 1 (MFMA): S_c = Kf^T[288x128] @ [V|1|pad][128x80] per (b,h,chunk).
// Kf A-fragments generated on the fly (bf16) per 32-row k-slice, double-
// buffered so gen(kt+1) overlaps MFMA(kt).  Ones column -> u_c for free.
// Fragment-major LDS layout as attn_mfma.  Epilogue: fp32 S, u (f<273).
// ---------------------------------------------------------------------------
__global__ __launch_bounds__(256) void chunk_sums_mfma(
    const float* __restrict__ qkb, const float* __restrict__ vbuf,
    float* __restrict__ Sbuf, float* __restrict__ ubuf) {
  const int c = blockIdx.x, bh = blockIdx.y;
  const int b = bh >> 4, h = bh & 15;
  const int tid = threadIdx.x;
  const int lane = tid & 63, w = tid >> 6;
  const int row0 = b * LSEQ + c * CHUNK;

  __shared__ float ksT[16 * 132];   // 8.4 KB: k transposed [d][i], stride 132
  __shared__ short Vp[20 * 512];    // 20 KB:  B-operand [V | 1 | 0-pad]
  __shared__ short Kf[2][18 * 512]; // 36 KB:  A-operand dbuf (one 32-k slice)

  // ---- stage ksT (k transposed; stride 132 -> 2-way-free banks) ----
  {
    int i = tid >> 1, d0 = (tid & 1) * 8;
    const float* src = qkb + (size_t)(row0 + i) * 512 + 256 + h * 16 + d0;
    float4 v0 = *(const float4*)src;
    float4 v1 = *(const float4*)(src + 4);
    ksT[(d0 + 0) * 132 + i] = v0.x; ksT[(d0 + 1) * 132 + i] = v0.y;
    ksT[(d0 + 2) * 132 + i] = v0.z; ksT[(d0 + 3) * 132 + i] = v0.w;
    ksT[(d0 + 4) * 132 + i] = v1.x; ksT[(d0 + 5) * 132 + i] = v1.y;
    ksT[(d0 + 6) * 132 + i] = v1.z; ksT[(d0 + 7) * 132 + i] = v1.w;
  }
  // ---- stage Vp = [V | 1 | 0-pad] (B-operand, N=80, K=128) ----
  for (int t = tid; t < 1280; t += 256) {
    int e, jg;
    if (t < 1024) { e = t & 63; jg = t >> 6; }
    else { int x = t - 1024; e = 64 + (x & 15); jg = x >> 4; }
    bf16x8 v8;
#pragma unroll
    for (int jj = 0; jj < 8; jj++) {
      float val;
      if (e < 64) val = vbuf[(size_t)(row0 + jg * 8 + jj) * (NH * DV) + h * DV + e];
      else val = (e == 64) ? 1.0f : 0.0f;
      v8[jj] = (short)f2bf(val);
    }
    *(bf16x8*)(Vp + ((e >> 4) * 4 + (jg >> 2)) * 512 + ((jg & 3) * 16 + (e & 15)) * 8) = v8;
  }
  __syncthreads();

  // ---- kf-slice generator: rows i0..i0+31 of Kf^T into Kf[kt&1] ----
  auto gen = [&](int kt) {
    for (int o = tid; o < 1152; o += 256) {
      int mt = o >> 6, w6 = o & 63;
      int kh = w6 >> 4, m = w6 & 15;
      int f = mt * 16 + m;
      int i0 = kt * 32 + kh * 8;
      bf16x8 v8;
      if (f == 0) {
#pragma unroll
        for (int j = 0; j < 8; j++) v8[j] = (short)0x3F80;  // 1.0 bf16
      } else if (f < 17) {
        const float* ka = &ksT[(f - 1) * 132 + i0];
        float4 a0 = *(const float4*)ka, a1 = *(const float4*)(ka + 4);
        v8[0] = (short)f2bf(0.5f * a0.x); v8[1] = (short)f2bf(0.5f * a0.y);
        v8[2] = (short)f2bf(0.5f * a0.z); v8[3] = (short)f2bf(0.5f * a0.w);
        v8[4] = (short)f2bf(0.5f * a1.x); v8[5] = (short)f2bf(0.5f * a1.y);
        v8[6] = (short)f2bf(0.5f * a1.z); v8[7] = (short)f2bf(0.5f * a1.w);
      } else if (f < FDIM) {
        int ix = f - 17;
        const float* ka = &ksT[(ix >> 4) * 132 + i0];
        const float* kb2 = &ksT[(ix & 15) * 132 + i0];
        float4 a0 = *(const float4*)ka, a1 = *(const float4*)(ka + 4);
        float4 b0 = *(const float4*)kb2, b1 = *(const float4*)(kb2 + 4);
        v8[0] = (short)f2bf(C2 * a0.x * b0.x); v8[1] = (short)f2bf(C2 * a0.y * b0.y);
        v8[2] = (short)f2bf(C2 * a0.z * b0.z); v8[3] = (short)f2bf(C2 * a0.w * b0.w);
        v8[4] = (short)f2bf(C2 * a1.x * b1.x); v8[5] = (short)f2bf(C2 * a1.y * b1.y);
        v8[6] = (short)f2bf(C2 * a1.z * b1.z); v8[7] = (short)f2bf(C2 * a1.w * b1.w);
      } else {
#pragma unroll
        for (int j = 0; j < 8; j++) v8[j] = 0;
      }
      *(bf16x8*)(Kf[kt & 1] + mt * 512 + (kh * 16 + m) * 8) = v8;
    }
  };

  gen(0);
  __syncthreads();

  f32x4 acc[5][5] = {};
  const int nmt = (w < 2) ? 5 : 4;  // m-tiles per wave (18 total, stride 4)
  for (int kt = 0; kt < 4; kt++) {
    if (kt < 3) gen(kt + 1);  // writes buf (kt+1)&1 while MFMA reads kt&1
    bf16x8 bv[5];
#pragma unroll
    for (int nt = 0; nt < 5; nt++)
      bv[nt] = *(const bf16x8*)(Vp + (nt * 4 + kt) * 512 + lane * 8);
    for (int t2 = 0; t2 < nmt; t2++) {
      int mt = w + t2 * 4;
      bf16x8 av = *(const bf16x8*)(Kf[kt & 1] + mt * 512 + lane * 8);
#pragma unroll
      for (int nt = 0; nt < 5; nt++)
        acc[t2][nt] = __builtin_amdgcn_mfma_f32_16x16x32_bf16(av, bv[nt], acc[t2][nt], 0, 0, 0);
    }
    __syncthreads();
  }

  // ---- epilogue: C/D layout col=lane&15, row=(lane>>4)*4+reg ----
  const int cl = lane & 15, r0q = (lane >> 4) * 4;
  const size_t sbase = ((size_t)bh * NCH + c) * FDIM;
  for (int t2 = 0; t2 < nmt; t2++) {
    int mt = w + t2 * 4;
#pragma unroll
    for (int reg = 0; reg < 4; reg++) {
      int f = mt * 16 + r0q + reg;
      if (f < FDIM) {
#pragma unroll
        for (int nt = 0; nt < 4; nt++)
          Sbuf[(sbase + f) * DV + nt * 16 + cl] = acc[t2][nt][reg];
        if (cl == 0) ubuf[sbase + f] = acc[t2][4][reg];
      }
    }
  }
}

// ---------------------------------------------------------------------------
// Pass 2: in-place exclusive prefix over chunks for S and u.
// ---------------------------------------------------------------------------
__global__ __launch_bounds__(64) void prefix_scan(float* __restrict__ Sbuf,
                                                  float* __restrict__ ubuf) {
  const int e = threadIdx.x;
  const int f = blockIdx.x % FDIM;
  const int bh = blockIdx.x / FDIM;
  size_t base = ((size_t)bh * NCH * FDIM + f) * DV + e;
  float run = 0.f;
  for (int c = 0; c < NCH; c++) {
    size_t off = base + (size_t)c * FDIM * DV;
    float t = Sbuf[off]; Sbuf[off] = run; run += t;
  }
  if (e == 0) {
    size_t bu = (size_t)bh * NCH * FDIM + f;
    float ru = 0.f;
    for (int c = 0; c < NCH; c++) {
      float t = ubuf[bu + (size_t)c * FDIM];
      ubuf[bu + (size_t)c * FDIM] = ru; ru += t;
    }
  }
}

// ---------------------------------------------------------------------------
// Pass 3 (MFMA): per-(b,h,chunk) outputs -> bf16 y.
//   S = Q·K^T (16x16x32 MFMA, K padded 16->32), A = poly(S) masked -> LDS
//   Y = A·[V|1]  (den via ones column)  then  Y += Qf·[P|u] in 9 k-tiles.
// ---------------------------------------------------------------------------
__global__ __launch_bounds__(256) void attn_mfma(
    const float* __restrict__ qkb, const float* __restrict__ vbuf,
    const float* __restrict__ Sbuf, const float* __restrict__ ubuf,
    unsigned short* __restrict__ ybuf) {
  const int c = blockIdx.x, bh = blockIdx.y;
  const int b = bh >> 4, h = bh & 15;
  const int tid = threadIdx.x;
  const int lane = tid & 63, w = tid >> 6;
  const int row0 = b * LSEQ + c * CHUNK;

  __shared__ short Am[16384];   // 32 KB
  __shared__ short QKV[10240];  // 20 KB
  __shared__ float qsF[2048];   // 8 KB
  __shared__ float denL[128];

  {
    int i = tid >> 1, d0 = (tid & 1) * 8;
    const float* src = qkb + (size_t)(row0 + i) * 512 + h * 16 + d0;
    float4 v0 = *(const float4*)src;
    float4 v1 = *(const float4*)(src + 4);
    *(float4*)&qsF[i * 16 + d0] = v0;
    *(float4*)&qsF[i * 16 + d0 + 4] = v1;
  }
  for (int t = tid; t < 1024; t += 256) {
    int isK = t >> 9;
    int tt = t & 511;
    int i = tt >> 2, kh = tt & 3;
    bf16x8 v8 = {0, 0, 0, 0, 0, 0, 0, 0};
    if (kh < 2) {
      const float* src = qkb + (size_t)(row0 + i) * 512 + isK * 256 + h * 16 + kh * 8;
      float4 a = *(const float4*)src;
      float4 bq = *(const float4*)(src + 4);
      v8[0] = (short)f2bf(a.x);  v8[1] = (short)f2bf(a.y);
      v8[2] = (short)f2bf(a.z);  v8[3] = (short)f2bf(a.w);
      v8[4] = (short)f2bf(bq.x); v8[5] = (short)f2bf(bq.y);
      v8[6] = (short)f2bf(bq.z); v8[7] = (short)f2bf(bq.w);
    }
    *(bf16x8*)(QKV + isK * 4096 + (i >> 4) * 512 + (kh * 16 + (i & 15)) * 8) = v8;
  }
  __syncthreads();

  {
    bf16x8 aq[2];
#pragma unroll
    for (int mi = 0; mi < 2; mi++)
      aq[mi] = *(const bf16x8*)(QKV + (w * 2 + mi) * 512 + lane * 8);
    f32x4 S[2][8] = {};
#pragma unroll
    for (int nt = 0; nt < 8; nt++) {
      bf16x8 bk = *(const bf16x8*)(QKV + 4096 + nt * 512 + lane * 8);
#pragma unroll
      for (int mi = 0; mi < 2; mi++)
        S[mi][nt] = __builtin_amdgcn_mfma_f32_16x16x32_bf16(aq[mi], bk, S[mi][nt], 0, 0, 0);
    }
    const int cl = lane & 15, r0q = (lane >> 4) * 4;
#pragma unroll
    for (int mi = 0; mi < 2; mi++)
#pragma unroll
      for (int nt = 0; nt < 8; nt++)
#pragma unroll
        for (int reg = 0; reg < 4; reg++) {
          int i = (w * 2 + mi) * 16 + r0q + reg;
          int j = nt * 16 + cl;
          float s = S[mi][nt][reg];
          float aij = (j <= i) ? fmaf(s, fmaf(s, 0.03125f, 0.25f), 1.0f) : 0.0f;
          Am[((i >> 4) * 4 + (j >> 5)) * 512 + (((j >> 3) & 3) * 16 + (i & 15)) * 8 + (j & 7)] =
              (short)f2bf(aij);
        }
  }
  __syncthreads();

  for (int t = tid; t < 1280; t += 256) {
    int e, jg;
    if (t < 1024) { e = t & 63; jg = t >> 6; }
    else { int x = t - 1024; e = 64 + (x & 15); jg = x >> 4; }
    bf16x8 v8;
#pragma unroll
    for (int jj = 0; jj < 8; jj++) {
      float val;
      if (e < 64) val = vbuf[(size_t)(row0 + jg * 8 + jj) * (NH * DV) + h * DV + e];
      else val = (e == 64) ? 1.0f : 0.0f;
      v8[jj] = (short)f2bf(val);
    }
    *(bf16x8*)(QKV + ((e >> 4) * 4 + (jg >> 2)) * 512 + ((jg & 3) * 16 + (e & 15)) * 8) = v8;
  }
  __syncthreads();

  f32x4 Y[2][5] = {};
#pragma unroll
  for (int kc = 0; kc < 4; kc++) {
    bf16x8 a2[2];
#pragma unroll
    for (int mi = 0; mi < 2; mi++)
      a2[mi] = *(const bf16x8*)(Am + ((w * 2 + mi) * 4 + kc) * 512 + lane * 8);
#pragma unroll
    for (int nt = 0; nt < 5; nt++) {
      bf16x8 b2 = *(const bf16x8*)(QKV + (nt * 4 + kc) * 512 + lane * 8);
#pragma unroll
      for (int mi = 0; mi < 2; mi++)
        Y[mi][nt] = __builtin_amdgcn_mfma_f32_16x16x32_bf16(a2[mi], b2, Y[mi][nt], 0, 0, 0);
    }
  }

  const size_t sbase = ((size_t)bh * NCH + c) * FDIM;
  for (int ft = 0; ft < 9; ft++) {
    const int f0 = ft * 32;
    __syncthreads();
    for (int t = tid; t < 512; t += 256) {
      int i = t >> 2, fh = t & 3;
      bf16x8 v8;
#pragma unroll
      for (int e2 = 0; e2 < 8; e2++) {
        int f = f0 + fh * 8 + e2;
        float qf;
        if (f == 0) qf = 1.0f;
        else if (f < 17) qf = 0.5f * qsF[i * 16 + f - 1];
        else if (f < FDIM) {
          int ix = f - 17;
          qf = C2 * qsF[i * 16 + (ix >> 4)] * qsF[i * 16 + (ix & 15)];
        } else qf = 0.0f;
        v8[e2] = (short)f2bf(qf);
      }
      *(bf16x8*)(Am + (i >> 4) * 512 + (fh * 16 + (i & 15)) * 8) = v8;
    }
    for (int t = tid; t < 320; t += 256) {
      int e, fg;
      if (t < 256) { e = t & 63; fg = t >> 6; }
      else { int x = t - 256; e = 64 + (x & 15); fg = x >> 4; }
      bf16x8 v8;
#pragma unroll
      for (int ff = 0; ff < 8; ff++) {
        int f = f0 + fg * 8 + ff;
        float val = 0.0f;
        if (f < FDIM) {
          if (e < 64) val = Sbuf[(sbase + f) * DV + e];
          else if (e == 64) val = ubuf[sbase + f];
        }
        v8[ff] = (short)f2bf(val);
      }
      *(bf16x8*)(Am + 4096 + (e >> 4) * 512 + (fg * 16 + (e & 15)) * 8) = v8;
    }
    __syncthreads();
    bf16x8 a3[2];
#pragma unroll
    for (int mi = 0; mi < 2; mi++)
      a3[mi] = *(const bf16x8*)(Am + (w * 2 + mi) * 512 + lane * 8);
#pragma unroll
    for (int nt = 0; nt < 5; nt++) {
      bf16x8 b3 = *(const bf16x8*)(Am + 4096 + nt * 512 + lane * 8);
#pragma unroll
      for (int mi = 0; mi < 2; mi++)
        Y[mi][nt] = __builtin_amdgcn_mfma_f32_16x16x32_bf16(a3[mi], b3, Y[mi][nt], 0, 0, 0);
    }
  }

  const int cl = lane & 15, r0q = (lane >> 4) * 4;
  if (cl == 0) {
#pragma unroll
    for (int mi = 0; mi < 2; mi++)
#pragma unroll
      for (int reg = 0; reg < 4; reg++)
        denL[(w * 2 + mi) * 16 + r0q + reg] = Y[mi][4][reg];
  }
  __syncthreads();
#pragma unroll
  for (int mi = 0; mi < 2; mi++) {
    float invd[4];
#pragma unroll
    for (int reg = 0; reg < 4; reg++)
      invd[reg] = 1.0f / (denL[(w * 2 + mi) * 16 + r0q + reg] + 1e-12f);
#pragma unroll
    for (int nt = 0; nt < 4; nt++)
#pragma unroll
      for (int reg = 0; reg < 4; reg++) {
        int i = (w * 2 + mi) * 16 + r0q + reg;
        int e = nt * 16 + cl;
        ybuf[(size_t)(row0 + i) * (NH * DV) + h * DV + e] =
            f2bf(Y[mi][nt][reg] * invd[reg]);
      }
  }
}

// ---------------------------------------------------------------------------
extern "C" void kernel_launch(void* const* d_in, const int* in_sizes, int n_in,
                              void* d_out, int out_size, void* d_ws, size_t ws_size,
                              hipStream_t stream) {
  const float* hs = (const float*)d_in[0];
  const float* Wq = (const float*)d_in[1];
  const float* Wk = (const float*)d_in[2];
  const float* Wv = (const float*)d_in[3];
  const float* Wo = (const float*)d_in[4];
  float* out = (float*)d_out;

  // workspace layout (~73 MB)
  float* qkb = (float*)d_ws;                              // 4096 x 512 f32 (q|k)
  float* vb  = qkb + (size_t)ROWS * 512;                  // 4096 x 1024 f32
  float* Sb  = vb + (size_t)ROWS * (NH * DV);             // 512*273*64 f32
  float* ub  = Sb + (size_t)BATCH * NH * NCH * FDIM * DV; // 512*273 f32
  unsigned short* hsb = (unsigned short*)(ub + (size_t)BATCH * NH * NCH * FDIM);
  unsigned short* yb  = hsb;  // alias: hsb dead after projection GEMMs
  unsigned short* wqt = hsb + (size_t)ROWS * DMODEL;      // 256x1024 bf16
  unsigned short* wkt = wqt + (size_t)(NH * DQK) * DMODEL; // (adjacent -> [Wq|Wk]^T)
  unsigned short* wvt = wkt + (size_t)(NH * DQK) * DMODEL; // 1024x1024 bf16
  unsigned short* wot = wvt + (size_t)(NH * DV) * DMODEL;  // 1024x1024 bf16

  // casts / transposes
  cast4<<<dim3((ROWS * DMODEL / 4 + 255) / 256), 256, 0, stream>>>(hs, hsb, ROWS * DMODEL / 4);
  transpose_cast<<<dim3((NH * DQK) / 32, DMODEL / 32), 256, 0, stream>>>(Wq, wqt, DMODEL, NH * DQK);
  transpose_cast<<<dim3((NH * DQK) / 32, DMODEL / 32), 256, 0, stream>>>(Wk, wkt, DMODEL, NH * DQK);
  transpose_cast<<<dim3((NH * DV) / 32, DMODEL / 32), 256, 0, stream>>>(Wv, wvt, DMODEL, NH * DV);
  transpose_cast<<<dim3(DMODEL / 32, DMODEL / 32), 256, 0, stream>>>(Wo, wot, DMODEL, DMODEL);

  // projections (MFMA): merged q|k (N=512), v (N=1024)
  gemm_mfma<<<dim3(512 / 128, ROWS / 128), 256, 0, stream>>>(hsb, wqt, qkb, ROWS, 512, DMODEL);
  gemm_mfma<<<dim3((NH * DV) / 128, ROWS / 128), 256, 0, stream>>>(hsb, wvt, vb, ROWS, NH * DV, DMODEL);

  // chunked causal linear attention
  chunk_sums_mfma<<<dim3(NCH, BATCH * NH), 256, 0, stream>>>(qkb, vb, Sb, ub);
  prefix_scan<<<dim3(BATCH * NH * FDIM), 64, 0, stream>>>(Sb, ub);
  attn_mfma<<<dim3(NCH, BATCH * NH), 256, 0, stream>>>(qkb, vb, Sb, ub, yb);

  // output projection (MFMA)
  gemm_mfma<<<dim3(DMODEL / 128, ROWS / 128), 256, 0, stream>>>(yb, wot, out, ROWS, DMODEL, DMODEL);
}

// Round 6
// 260.924 us; speedup vs baseline: 1.3022x; 1.3022x over previous
//
#include <hip/hip_runtime.h>
#include <hip/hip_bf16.h>

// Problem constants
#define BATCH 2
#define LSEQ 2048
#define DMODEL 1024
#define NH 16
#define DQK 16
#define DV 64
#define FDIM 273            // 1 + 16 + 256
#define CHUNK 128
#define NCH (LSEQ / CHUNK)  // 16 chunks per batch row
#define ROWS (BATCH * LSEQ) // 4096
#define C2 0.17677669529663687f  // 1/(4*sqrt(2))

typedef short bf16x8 __attribute__((ext_vector_type(8)));
typedef float f32x4 __attribute__((ext_vector_type(4)));

__device__ __forceinline__ unsigned short f2bf(float f) {
  __hip_bfloat16 h = __float2bfloat16(f);
  unsigned short u; __builtin_memcpy(&u, &h, 2); return u;
}

// ---------------------------------------------------------------------------
// fp32 -> bf16 elementwise cast (float4 / ushort4 vectorized)
// ---------------------------------------------------------------------------
__global__ __launch_bounds__(256) void cast4(const float* __restrict__ in,
                                             unsigned short* __restrict__ out, int n4) {
  int i = blockIdx.x * 256 + threadIdx.x;
  if (i >= n4) return;
  float4 v = ((const float4*)in)[i];
  ushort4 o = {f2bf(v.x), f2bf(v.y), f2bf(v.z), f2bf(v.w)};
  ((ushort4*)out)[i] = o;
}

// ---------------------------------------------------------------------------
// W (KxN fp32, row-major) -> Wt (NxK bf16, row-major).  32x32 LDS tile.
// ---------------------------------------------------------------------------
__global__ __launch_bounds__(256) void transpose_cast(
    const float* __restrict__ W, unsigned short* __restrict__ Wt, int K, int N) {
  __shared__ float t[32][33];
  const int kb = blockIdx.y * 32, nb = blockIdx.x * 32;
  const int tx = threadIdx.x & 31, ty4 = (threadIdx.x >> 5) * 4;
#pragma unroll
  for (int r = 0; r < 4; r++)
    t[ty4 + r][tx] = W[(size_t)(kb + ty4 + r) * N + nb + tx];
  __syncthreads();
#pragma unroll
  for (int r = 0; r < 4; r++)
    Wt[(size_t)(nb + ty4 + r) * K + kb + tx] = f2bf(t[tx][ty4 + r]);
}

// ---------------------------------------------------------------------------
// MFMA GEMM (m97 pattern): C(MxN fp32) = A(MxK bf16) @ Bt(NxK bf16)^T.
// 128x128 tile, BK=32, 256 threads = 4 waves, each wave a 64x64 quadrant.
// ---------------------------------------------------------------------------
__global__ __launch_bounds__(256) void gemm_mfma(
    const unsigned short* __restrict__ A, const unsigned short* __restrict__ Bt,
    float* __restrict__ C, int M, int N, int K) {
  __shared__ unsigned short As[512 * 8];
  __shared__ unsigned short Bs[512 * 8];
  const int tid = threadIdx.x;
  const int bm = blockIdx.y * 128, bn = blockIdx.x * 128;
  const int lane = tid & 63;
  const int w = tid >> 6;
  const int qr = (w >> 1) * 64, qc = (w & 1) * 64;
  f32x4 acc[4][4] = {};

  for (int k0 = 0; k0 < K; k0 += 32) {
#pragma unroll
    for (int j = 0; j < 4; ++j) {
      int c = j * 256 + tid;
      int cc = c & 511;
      int row = ((cc >> 6) << 4) + (cc & 15);
      int kh = (cc >> 4) & 3;
      const unsigned short* gp;
      unsigned short* lp;
      if (c < 512) { gp = A  + (size_t)(bm + row) * K + k0 + kh * 8; lp = As + cc * 8; }
      else         { gp = Bt + (size_t)(bn + row) * K + k0 + kh * 8; lp = Bs + cc * 8; }
      __builtin_amdgcn_global_load_lds(
          (const __attribute__((address_space(1))) unsigned int*)(const void*)gp,
          (__attribute__((address_space(3))) unsigned int*)lp, 16, 0, 0);
    }
    __syncthreads();
    bf16x8 a[4], b[4];
#pragma unroll
    for (int i = 0; i < 4; ++i) {
      a[i] = *(const bf16x8*)(As + ((qr >> 4) + i) * 512 + lane * 8);
      b[i] = *(const bf16x8*)(Bs + ((qc >> 4) + i) * 512 + lane * 8);
    }
#pragma unroll
    for (int i = 0; i < 4; ++i)
#pragma unroll
      for (int jj = 0; jj < 4; ++jj)
        acc[i][jj] = __builtin_amdgcn_mfma_f32_16x16x32_bf16(a[i], b[jj], acc[i][jj], 0, 0, 0);
    __syncthreads();
  }
  const int cn = lane & 15, r0 = (lane >> 4) * 4;
#pragma unroll
  for (int i = 0; i < 4; ++i)
#pragma unroll
    for (int jj = 0; jj < 4; ++jj) {
      size_t base = (size_t)(bm + qr + i * 16 + r0) * N + bn + qc + jj * 16 + cn;
#pragma unroll
      for (int r = 0; r < 4; ++r) C[base + (size_t)r * N] = acc[i][jj][r];
    }
}

// ---------------------------------------------------------------------------
// Pass 1 (MFMA): S_c = Kf^T[288x128] @ [V|1|pad][128x80] per (b,h,chunk).
// Kf A-fragments generated on the fly (bf16) per 32-row k-slice, double-
// buffered so gen(kt+1) overlaps MFMA(kt).  Ones column -> u_c for free.
// NOTE: all acc[] indices are compile-time (full unroll + uniform predicate);
// a runtime-bound loop here demotes acc to scratch -> 267 MB spill traffic (R5).
// ---------------------------------------------------------------------------
__global__ __launch_bounds__(256) void chunk_sums_mfma(
    const float* __restrict__ qkb, const float* __restrict__ vbuf,
    float* __restrict__ Sbuf, float* __restrict__ ubuf) {
  const int c = blockIdx.x, bh = blockIdx.y;
  const int b = bh >> 4, h = bh & 15;
  const int tid = threadIdx.x;
  const int lane = tid & 63, w = tid >> 6;
  const int row0 = b * LSEQ + c * CHUNK;

  __shared__ float ksT[16 * 132];   // 8.4 KB: k transposed [d][i], stride 132
  __shared__ short Vp[20 * 512];    // 20 KB:  B-operand [V | 1 | 0-pad]
  __shared__ short Kf[2][18 * 512]; // 36 KB:  A-operand dbuf (one 32-k slice)

  // ---- stage ksT (k transposed; stride 132 -> 2-way-free banks) ----
  {
    int i = tid >> 1, d0 = (tid & 1) * 8;
    const float* src = qkb + (size_t)(row0 + i) * 512 + 256 + h * 16 + d0;
    float4 v0 = *(const float4*)src;
    float4 v1 = *(const float4*)(src + 4);
    ksT[(d0 + 0) * 132 + i] = v0.x; ksT[(d0 + 1) * 132 + i] = v0.y;
    ksT[(d0 + 2) * 132 + i] = v0.z; ksT[(d0 + 3) * 132 + i] = v0.w;
    ksT[(d0 + 4) * 132 + i] = v1.x; ksT[(d0 + 5) * 132 + i] = v1.y;
    ksT[(d0 + 6) * 132 + i] = v1.z; ksT[(d0 + 7) * 132 + i] = v1.w;
  }
  // ---- stage Vp = [V | 1 | 0-pad] (B-operand, N=80, K=128) ----
  for (int t = tid; t < 1280; t += 256) {
    int e, jg;
    if (t < 1024) { e = t & 63; jg = t >> 6; }
    else { int x = t - 1024; e = 64 + (x & 15); jg = x >> 4; }
    bf16x8 v8;
#pragma unroll
    for (int jj = 0; jj < 8; jj++) {
      float val;
      if (e < 64) val = vbuf[(size_t)(row0 + jg * 8 + jj) * (NH * DV) + h * DV + e];
      else val = (e == 64) ? 1.0f : 0.0f;
      v8[jj] = (short)f2bf(val);
    }
    *(bf16x8*)(Vp + ((e >> 4) * 4 + (jg >> 2)) * 512 + ((jg & 3) * 16 + (e & 15)) * 8) = v8;
  }
  __syncthreads();

  // ---- kf-slice generator: rows i0..i0+31 of Kf^T into Kf[kt&1] ----
  auto gen = [&](int kt) {
    for (int o = tid; o < 1152; o += 256) {
      int mt = o >> 6, w6 = o & 63;
      int kh = w6 >> 4, m = w6 & 15;
      int f = mt * 16 + m;
      int i0 = kt * 32 + kh * 8;
      bf16x8 v8;
      if (f == 0) {
#pragma unroll
        for (int j = 0; j < 8; j++) v8[j] = (short)0x3F80;  // 1.0 bf16
      } else if (f < 17) {
        const float* ka = &ksT[(f - 1) * 132 + i0];
        float4 a0 = *(const float4*)ka, a1 = *(const float4*)(ka + 4);
        v8[0] = (short)f2bf(0.5f * a0.x); v8[1] = (short)f2bf(0.5f * a0.y);
        v8[2] = (short)f2bf(0.5f * a0.z); v8[3] = (short)f2bf(0.5f * a0.w);
        v8[4] = (short)f2bf(0.5f * a1.x); v8[5] = (short)f2bf(0.5f * a1.y);
        v8[6] = (short)f2bf(0.5f * a1.z); v8[7] = (short)f2bf(0.5f * a1.w);
      } else if (f < FDIM) {
        int ix = f - 17;
        const float* ka = &ksT[(ix >> 4) * 132 + i0];
        const float* kb2 = &ksT[(ix & 15) * 132 + i0];
        float4 a0 = *(const float4*)ka, a1 = *(const float4*)(ka + 4);
        float4 b0 = *(const float4*)kb2, b1 = *(const float4*)(kb2 + 4);
        v8[0] = (short)f2bf(C2 * a0.x * b0.x); v8[1] = (short)f2bf(C2 * a0.y * b0.y);
        v8[2] = (short)f2bf(C2 * a0.z * b0.z); v8[3] = (short)f2bf(C2 * a0.w * b0.w);
        v8[4] = (short)f2bf(C2 * a1.x * b1.x); v8[5] = (short)f2bf(C2 * a1.y * b1.y);
        v8[6] = (short)f2bf(C2 * a1.z * b1.z); v8[7] = (short)f2bf(C2 * a1.w * b1.w);
      } else {
#pragma unroll
        for (int j = 0; j < 8; j++) v8[j] = 0;
      }
      *(bf16x8*)(Kf[kt & 1] + mt * 512 + (kh * 16 + m) * 8) = v8;
    }
  };

  gen(0);
  __syncthreads();

  f32x4 acc[5][5] = {};
  const int nmt = (w < 2) ? 5 : 4;  // m-tiles per wave (18 total, stride 4)
  for (int kt = 0; kt < 4; kt++) {
    if (kt < 3) gen(kt + 1);  // writes buf (kt+1)&1 while MFMA reads kt&1
    bf16x8 bv[5];
#pragma unroll
    for (int nt = 0; nt < 5; nt++)
      bv[nt] = *(const bf16x8*)(Vp + (nt * 4 + kt) * 512 + lane * 8);
#pragma unroll
    for (int t2 = 0; t2 < 5; t2++) {
      if (t2 < nmt) {  // wave-uniform predicate; indices stay compile-time
        int mt = w + t2 * 4;
        bf16x8 av = *(const bf16x8*)(Kf[kt & 1] + mt * 512 + lane * 8);
#pragma unroll
        for (int nt = 0; nt < 5; nt++)
          acc[t2][nt] = __builtin_amdgcn_mfma_f32_16x16x32_bf16(av, bv[nt], acc[t2][nt], 0, 0, 0);
      }
    }
    __syncthreads();
  }

  // ---- epilogue: C/D layout col=lane&15, row=(lane>>4)*4+reg ----
  const int cl = lane & 15, r0q = (lane >> 4) * 4;
  const size_t sbase = ((size_t)bh * NCH + c) * FDIM;
#pragma unroll
  for (int t2 = 0; t2 < 5; t2++) {
    if (t2 < nmt) {
      int mt = w + t2 * 4;
#pragma unroll
      for (int reg = 0; reg < 4; reg++) {
        int f = mt * 16 + r0q + reg;
        if (f < FDIM) {
#pragma unroll
          for (int nt = 0; nt < 4; nt++)
            Sbuf[(sbase + f) * DV + nt * 16 + cl] = acc[t2][nt][reg];
          if (cl == 0) ubuf[sbase + f] = acc[t2][4][reg];
        }
      }
    }
  }
}

// ---------------------------------------------------------------------------
// Pass 2: in-place exclusive prefix over chunks for S and u.
// ---------------------------------------------------------------------------
__global__ __launch_bounds__(64) void prefix_scan(float* __restrict__ Sbuf,
                                                  float* __restrict__ ubuf) {
  const int e = threadIdx.x;
  const int f = blockIdx.x % FDIM;
  const int bh = blockIdx.x / FDIM;
  size_t base = ((size_t)bh * NCH * FDIM + f) * DV + e;
  float run = 0.f;
  for (int c = 0; c < NCH; c++) {
    size_t off = base + (size_t)c * FDIM * DV;
    float t = Sbuf[off]; Sbuf[off] = run; run += t;
  }
  if (e == 0) {
    size_t bu = (size_t)bh * NCH * FDIM + f;
    float ru = 0.f;
    for (int c = 0; c < NCH; c++) {
      float t = ubuf[bu + (size_t)c * FDIM];
      ubuf[bu + (size_t)c * FDIM] = ru; ru += t;
    }
  }
}

// ---------------------------------------------------------------------------
// Pass 3 (MFMA): per-(b,h,chunk) outputs -> bf16 y.
//   S = Q·K^T (16x16x32 MFMA, K padded 16->32), A = poly(S) masked -> LDS
//   Y = A·[V|1]  (den via ones column)  then  Y += Qf·[P|u] in 9 k-tiles.
// ---------------------------------------------------------------------------
__global__ __launch_bounds__(256) void attn_mfma(
    const float* __restrict__ qkb, const float* __restrict__ vbuf,
    const float* __restrict__ Sbuf, const float* __restrict__ ubuf,
    unsigned short* __restrict__ ybuf) {
  const int c = blockIdx.x, bh = blockIdx.y;
  const int b = bh >> 4, h = bh & 15;
  const int tid = threadIdx.x;
  const int lane = tid & 63, w = tid >> 6;
  const int row0 = b * LSEQ + c * CHUNK;

  __shared__ short Am[16384];   // 32 KB
  __shared__ short QKV[10240];  // 20 KB
  __shared__ float qsF[2048];   // 8 KB
  __shared__ float denL[128];

  {
    int i = tid >> 1, d0 = (tid & 1) * 8;
    const float* src = qkb + (size_t)(row0 + i) * 512 + h * 16 + d0;
    float4 v0 = *(const float4*)src;
    float4 v1 = *(const float4*)(src + 4);
    *(float4*)&qsF[i * 16 + d0] = v0;
    *(float4*)&qsF[i * 16 + d0 + 4] = v1;
  }
  for (int t = tid; t < 1024; t += 256) {
    int isK = t >> 9;
    int tt = t & 511;
    int i = tt >> 2, kh = tt & 3;
    bf16x8 v8 = {0, 0, 0, 0, 0, 0, 0, 0};
    if (kh < 2) {
      const float* src = qkb + (size_t)(row0 + i) * 512 + isK * 256 + h * 16 + kh * 8;
      float4 a = *(const float4*)src;
      float4 bq = *(const float4*)(src + 4);
      v8[0] = (short)f2bf(a.x);  v8[1] = (short)f2bf(a.y);
      v8[2] = (short)f2bf(a.z);  v8[3] = (short)f2bf(a.w);
      v8[4] = (short)f2bf(bq.x); v8[5] = (short)f2bf(bq.y);
      v8[6] = (short)f2bf(bq.z); v8[7] = (short)f2bf(bq.w);
    }
    *(bf16x8*)(QKV + isK * 4096 + (i >> 4) * 512 + (kh * 16 + (i & 15)) * 8) = v8;
  }
  __syncthreads();

  {
    bf16x8 aq[2];
#pragma unroll
    for (int mi = 0; mi < 2; mi++)
      aq[mi] = *(const bf16x8*)(QKV + (w * 2 + mi) * 512 + lane * 8);
    f32x4 S[2][8] = {};
#pragma unroll
    for (int nt = 0; nt < 8; nt++) {
      bf16x8 bk = *(const bf16x8*)(QKV + 4096 + nt * 512 + lane * 8);
#pragma unroll
      for (int mi = 0; mi < 2; mi++)
        S[mi][nt] = __builtin_amdgcn_mfma_f32_16x16x32_bf16(aq[mi], bk, S[mi][nt], 0, 0, 0);
    }
    const int cl = lane & 15, r0q = (lane >> 4) * 4;
#pragma unroll
    for (int mi = 0; mi < 2; mi++)
#pragma unroll
      for (int nt = 0; nt < 8; nt++)
#pragma unroll
        for (int reg = 0; reg < 4; reg++) {
          int i = (w * 2 + mi) * 16 + r0q + reg;
          int j = nt * 16 + cl;
          float s = S[mi][nt][reg];
          float aij = (j <= i) ? fmaf(s, fmaf(s, 0.03125f, 0.25f), 1.0f) : 0.0f;
          Am[((i >> 4) * 4 + (j >> 5)) * 512 + (((j >> 3) & 3) * 16 + (i & 15)) * 8 + (j & 7)] =
              (short)f2bf(aij);
        }
  }
  __syncthreads();

  for (int t = tid; t < 1280; t += 256) {
    int e, jg;
    if (t < 1024) { e = t & 63; jg = t >> 6; }
    else { int x = t - 1024; e = 64 + (x & 15); jg = x >> 4; }
    bf16x8 v8;
#pragma unroll
    for (int jj = 0; jj < 8; jj++) {
      float val;
      if (e < 64) val = vbuf[(size_t)(row0 + jg * 8 + jj) * (NH * DV) + h * DV + e];
      else val = (e == 64) ? 1.0f : 0.0f;
      v8[jj] = (short)f2bf(val);
    }
    *(bf16x8*)(QKV + ((e >> 4) * 4 + (jg >> 2)) * 512 + ((jg & 3) * 16 + (e & 15)) * 8) = v8;
  }
  __syncthreads();

  f32x4 Y[2][5] = {};
#pragma unroll
  for (int kc = 0; kc < 4; kc++) {
    bf16x8 a2[2];
#pragma unroll
    for (int mi = 0; mi < 2; mi++)
      a2[mi] = *(const bf16x8*)(Am + ((w * 2 + mi) * 4 + kc) * 512 + lane * 8);
#pragma unroll
    for (int nt = 0; nt < 5; nt++) {
      bf16x8 b2 = *(const bf16x8*)(QKV + (nt * 4 + kc) * 512 + lane * 8);
#pragma unroll
      for (int mi = 0; mi < 2; mi++)
        Y[mi][nt] = __builtin_amdgcn_mfma_f32_16x16x32_bf16(a2[mi], b2, Y[mi][nt], 0, 0, 0);
    }
  }

  const size_t sbase = ((size_t)bh * NCH + c) * FDIM;
  for (int ft = 0; ft < 9; ft++) {
    const int f0 = ft * 32;
    __syncthreads();
    for (int t = tid; t < 512; t += 256) {
      int i = t >> 2, fh = t & 3;
      bf16x8 v8;
#pragma unroll
      for (int e2 = 0; e2 < 8; e2++) {
        int f = f0 + fh * 8 + e2;
        float qf;
        if (f == 0) qf = 1.0f;
        else if (f < 17) qf = 0.5f * qsF[i * 16 + f - 1];
        else if (f < FDIM) {
          int ix = f - 17;
          qf = C2 * qsF[i * 16 + (ix >> 4)] * qsF[i * 16 + (ix & 15)];
        } else qf = 0.0f;
        v8[e2] = (short)f2bf(qf);
      }
      *(bf16x8*)(Am + (i >> 4) * 512 + (fh * 16 + (i & 15)) * 8) = v8;
    }
    for (int t = tid; t < 320; t += 256) {
      int e, fg;
      if (t < 256) { e = t & 63; fg = t >> 6; }
      else { int x = t - 256; e = 64 + (x & 15); fg = x >> 4; }
      bf16x8 v8;
#pragma unroll
      for (int ff = 0; ff < 8; ff++) {
        int f = f0 + fg * 8 + ff;
        float val = 0.0f;
        if (f < FDIM) {
          if (e < 64) val = Sbuf[(sbase + f) * DV + e];
          else if (e == 64) val = ubuf[sbase + f];
        }
        v8[ff] = (short)f2bf(val);
      }
      *(bf16x8*)(Am + 4096 + (e >> 4) * 512 + (fg * 16 + (e & 15)) * 8) = v8;
    }
    __syncthreads();
    bf16x8 a3[2];
#pragma unroll
    for (int mi = 0; mi < 2; mi++)
      a3[mi] = *(const bf16x8*)(Am + (w * 2 + mi) * 512 + lane * 8);
#pragma unroll
    for (int nt = 0; nt < 5; nt++) {
      bf16x8 b3 = *(const bf16x8*)(Am + 4096 + nt * 512 + lane * 8);
#pragma unroll
      for (int mi = 0; mi < 2; mi++)
        Y[mi][nt] = __builtin_amdgcn_mfma_f32_16x16x32_bf16(a3[mi], b3, Y[mi][nt], 0, 0, 0);
    }
  }

  const int cl = lane & 15, r0q = (lane >> 4) * 4;
  if (cl == 0) {
#pragma unroll
    for (int mi = 0; mi < 2; mi++)
#pragma unroll
      for (int reg = 0; reg < 4; reg++)
        denL[(w * 2 + mi) * 16 + r0q + reg] = Y[mi][4][reg];
  }
  __syncthreads();
#pragma unroll
  for (int mi = 0; mi < 2; mi++) {
    float invd[4];
#pragma unroll
    for (int reg = 0; reg < 4; reg++)
      invd[reg] = 1.0f / (denL[(w * 2 + mi) * 16 + r0q + reg] + 1e-12f);
#pragma unroll
    for (int nt = 0; nt < 4; nt++)
#pragma unroll
      for (int reg = 0; reg < 4; reg++) {
        int i = (w * 2 + mi) * 16 + r0q + reg;
        int e = nt * 16 + cl;
        ybuf[(size_t)(row0 + i) * (NH * DV) + h * DV + e] =
            f2bf(Y[mi][nt][reg] * invd[reg]);
      }
  }
}

// ---------------------------------------------------------------------------
extern "C" void kernel_launch(void* const* d_in, const int* in_sizes, int n_in,
                              void* d_out, int out_size, void* d_ws, size_t ws_size,
                              hipStream_t stream) {
  const float* hs = (const float*)d_in[0];
  const float* Wq = (const float*)d_in[1];
  const float* Wk = (const float*)d_in[2];
  const float* Wv = (const float*)d_in[3];
  const float* Wo = (const float*)d_in[4];
  float* out = (float*)d_out;

  // workspace layout (~73 MB)
  float* qkb = (float*)d_ws;                              // 4096 x 512 f32 (q|k)
  float* vb  = qkb + (size_t)ROWS * 512;                  // 4096 x 1024 f32
  float* Sb  = vb + (size_t)ROWS * (NH * DV);             // 512*273*64 f32
  float* ub  = Sb + (size_t)BATCH * NH * NCH * FDIM * DV; // 512*273 f32
  unsigned short* hsb = (unsigned short*)(ub + (size_t)BATCH * NH * NCH * FDIM);
  unsigned short* yb  = hsb;  // alias: hsb dead after projection GEMMs
  unsigned short* wqt = hsb + (size_t)ROWS * DMODEL;      // 256x1024 bf16
  unsigned short* wkt = wqt + (size_t)(NH * DQK) * DMODEL; // (adjacent -> [Wq|Wk]^T)
  unsigned short* wvt = wkt + (size_t)(NH * DQK) * DMODEL; // 1024x1024 bf16
  unsigned short* wot = wvt + (size_t)(NH * DV) * DMODEL;  // 1024x1024 bf16

  // casts / transposes
  cast4<<<dim3((ROWS * DMODEL / 4 + 255) / 256), 256, 0, stream>>>(hs, hsb, ROWS * DMODEL / 4);
  transpose_cast<<<dim3((NH * DQK) / 32, DMODEL / 32), 256, 0, stream>>>(Wq, wqt, DMODEL, NH * DQK);
  transpose_cast<<<dim3((NH * DQK) / 32, DMODEL / 32), 256, 0, stream>>>(Wk, wkt, DMODEL, NH * DQK);
  transpose_cast<<<dim3((NH * DV) / 32, DMODEL / 32), 256, 0, stream>>>(Wv, wvt, DMODEL, NH * DV);
  transpose_cast<<<dim3(DMODEL / 32, DMODEL / 32), 256, 0, stream>>>(Wo, wot, DMODEL, DMODEL);

  // projections (MFMA): merged q|k (N=512), v (N=1024)
  gemm_mfma<<<dim3(512 / 128, ROWS / 128), 256, 0, stream>>>(hsb, wqt, qkb, ROWS, 512, DMODEL);
  gemm_mfma<<<dim3((NH * DV) / 128, ROWS / 128), 256, 0, stream>>>(hsb, wvt, vb, ROWS, NH * DV, DMODEL);

  // chunked causal linear attention
  chunk_sums_mfma<<<dim3(NCH, BATCH * NH), 256, 0, stream>>>(qkb, vb, Sb, ub);
  prefix_scan<<<dim3(BATCH * NH * FDIM), 64, 0, stream>>>(Sb, ub);
  attn_mfma<<<dim3(NCH, BATCH * NH), 256, 0, stream>>>(qkb, vb, Sb, ub, yb);

  // output projection (MFMA)
  gemm_mfma<<<dim3(DMODEL / 128, ROWS / 128), 256, 0, stream>>>(yb, wot, out, ROWS, DMODEL, DMODEL);
}